// Round 1
// baseline (499.987 us; speedup 1.0000x reference)
//
#include <hip/hip_runtime.h>

#define FIN 256
#define FE  64
#define FOUT 256
#define KTOT 320   // FIN + FE

typedef __attribute__((ext_vector_type(8))) short short8;
typedef __attribute__((ext_vector_type(4))) float f32x4;

__device__ inline unsigned short f2bf(float f) {  // RNE
    unsigned int u = __builtin_bit_cast(unsigned int, f);
    u += 0x7fffu + ((u >> 16) & 1u);
    return (unsigned short)(u >> 16);
}
__device__ inline float bfu(unsigned short b) {
    return __builtin_bit_cast(float, (unsigned int)b << 16);
}

// ---------------- pass 1: degree histogram + weight transpose/bf16 (independent, merged) ----

__global__ void k_deg_prepw(const int* __restrict__ src, const int* __restrict__ dst,
                            int* __restrict__ out_deg, int* __restrict__ in_deg,
                            const float* __restrict__ w, unsigned short* __restrict__ wtt,
                            int E) {
    int i = blockIdx.x * blockDim.x + threadIdx.x;
    if (i < E) {
        atomicAdd(&out_deg[src[i]], 1);
        atomicAdd(&in_deg[dst[i]], 1);
    }
    if (i < KTOT * 256) {  // weight [320 k][256 n] f32 -> wtt [256 n][320 k] bf16
        int k = i >> 8, n = i & 255;
        wtt[n * KTOT + k] = f2bf(w[i]);
    }
}

// ---------------- pass 2: scan-free exclusive scan + degree norms ----------------

__global__ __launch_bounds__(1024) void k_scan(const int* __restrict__ in_deg,
                                               const int* __restrict__ out_deg,
                                               int* __restrict__ row_ptr,
                                               int* __restrict__ cursor,
                                               float* __restrict__ norm_out,
                                               float* __restrict__ norm_in, int N) {
    __shared__ int red[16];
    __shared__ int wsum[16];
    __shared__ int wo[17];
    int b = blockIdx.x, t = threadIdx.x;
    int lane = t & 63, w = t >> 6;
    int limit = b << 10;

    int part = 0;
    for (int i = t; i < limit; i += 1024) part += in_deg[i];
#pragma unroll
    for (int off = 32; off; off >>= 1) part += __shfl_down(part, off, 64);
    if (lane == 0) red[w] = part;
    __syncthreads();
    if (t == 0) {
        int s = 0;
#pragma unroll
        for (int k = 0; k < 16; k++) s += red[k];
        red[0] = s;
    }
    __syncthreads();
    int base = red[0];

    int i = limit + t;
    int v = (i < N) ? in_deg[i] : 0;
    int incl = v;
#pragma unroll
    for (int off = 1; off < 64; off <<= 1) {
        int x = __shfl_up(incl, off, 64);
        if (lane >= off) incl += x;
    }
    if (lane == 63) wsum[w] = incl;
    __syncthreads();
    if (w == 0 && lane < 16) {
        int s = wsum[lane];
        int sc = s;
#pragma unroll
        for (int off = 1; off < 16; off <<= 1) {
            int x = __shfl_up(sc, off, 64);
            if (lane >= off) sc += x;
        }
        wo[lane] = sc - s;
        if (lane == 15) wo[16] = sc;
    }
    __syncthreads();
    int excl = base + wo[w] + incl - v;
    if (i < N) {
        row_ptr[i] = excl;
        cursor[i] = excl;
        norm_in[i]  = 1.0f / sqrtf((float)max(v, 1));
        norm_out[i] = 1.0f / sqrtf((float)max(out_deg[i], 1));
    }
    if (t == 0 && i + 1024 > N && i < N + 1024) row_ptr[N] = base + wo[16];
}

// ---------------- pass 3: CSR scatter + feat->bf16 prescale (both post-scan, merged) ----

__global__ void k_scatter_prepf(const int* __restrict__ src, const int* __restrict__ dst,
                                int* __restrict__ cursor, int2* __restrict__ s_se, int E,
                                const float* __restrict__ feat,
                                const float* __restrict__ norm_out,
                                unsigned short* __restrict__ featb, int N) {
    int i = blockIdx.x * blockDim.x + threadIdx.x;
    if (i < E) {
        int d = dst[i];
        int p = atomicAdd(&cursor[d], 1);
        s_se[p] = make_int2(src[i], i);
    }
    if (i < N * 64) {
        int m = i >> 6, c4 = (i & 63) * 4;
        float s = norm_out[m];
        float4 v = *(const float4*)&feat[(size_t)m * FIN + c4];
        ushort4 o;
        o.x = f2bf(v.x * s); o.y = f2bf(v.y * s); o.z = f2bf(v.z * s); o.w = f2bf(v.w * s);
        *(ushort4*)&featb[(size_t)m * FIN + c4] = o;
    }
}

// ---------------- pass 4: fused CSR gather, 1 wave per node, 8-edge unroll ----------------
// Theory: this pass is latency-bound (two-level dependent gather), not BW-bound.
// 1 wave/node removes the LDS reduce + __syncthreads wave-coupling; 8-edge unroll
// keeps 16 data loads in flight per wave (same in-flight bytes/SIMD as the old
// 2-subwave x 4-unroll even if occupancy halves on VGPRs). The 8 int2 index
// loads per chunk sit in one 64B line of s_se (L1 broadcast).

__global__ __launch_bounds__(256) void k_agg(const unsigned short* __restrict__ featb,
                                             const float* __restrict__ edge_feat,
                                             const int* __restrict__ row_ptr,
                                             const int2* __restrict__ s_se,
                                             unsigned short* __restrict__ aggb, int N) {
    int t = threadIdx.x;
    int w = t >> 6, lane = t & 63;
    int n = blockIdx.x * 4 + w;
    if (n >= N) return;

    int beg = row_ptr[n], end = row_ptr[n + 1];
    float h0 = 0.f, h1 = 0.f, h2 = 0.f, h3 = 0.f, eacc = 0.f;
    int p = beg;

    for (; p + 8 <= end; p += 8) {
        int2 i0 = s_se[p + 0], i1 = s_se[p + 1], i2 = s_se[p + 2], i3 = s_se[p + 3];
        int2 i4 = s_se[p + 4], i5 = s_se[p + 5], i6 = s_se[p + 6], i7 = s_se[p + 7];
        ushort4 f0 = *(const ushort4*)&featb[(size_t)i0.x * FIN + lane * 4];
        ushort4 f1 = *(const ushort4*)&featb[(size_t)i1.x * FIN + lane * 4];
        ushort4 f2 = *(const ushort4*)&featb[(size_t)i2.x * FIN + lane * 4];
        ushort4 f3 = *(const ushort4*)&featb[(size_t)i3.x * FIN + lane * 4];
        ushort4 f4 = *(const ushort4*)&featb[(size_t)i4.x * FIN + lane * 4];
        ushort4 f5 = *(const ushort4*)&featb[(size_t)i5.x * FIN + lane * 4];
        ushort4 f6 = *(const ushort4*)&featb[(size_t)i6.x * FIN + lane * 4];
        ushort4 f7 = *(const ushort4*)&featb[(size_t)i7.x * FIN + lane * 4];
        float e0 = __builtin_nontemporal_load(&edge_feat[(size_t)i0.y * FE + lane]);
        float e1 = __builtin_nontemporal_load(&edge_feat[(size_t)i1.y * FE + lane]);
        float e2 = __builtin_nontemporal_load(&edge_feat[(size_t)i2.y * FE + lane]);
        float e3 = __builtin_nontemporal_load(&edge_feat[(size_t)i3.y * FE + lane]);
        float e4 = __builtin_nontemporal_load(&edge_feat[(size_t)i4.y * FE + lane]);
        float e5 = __builtin_nontemporal_load(&edge_feat[(size_t)i5.y * FE + lane]);
        float e6 = __builtin_nontemporal_load(&edge_feat[(size_t)i6.y * FE + lane]);
        float e7 = __builtin_nontemporal_load(&edge_feat[(size_t)i7.y * FE + lane]);
        h0 += ((bfu(f0.x) + bfu(f1.x)) + (bfu(f2.x) + bfu(f3.x))) +
              ((bfu(f4.x) + bfu(f5.x)) + (bfu(f6.x) + bfu(f7.x)));
        h1 += ((bfu(f0.y) + bfu(f1.y)) + (bfu(f2.y) + bfu(f3.y))) +
              ((bfu(f4.y) + bfu(f5.y)) + (bfu(f6.y) + bfu(f7.y)));
        h2 += ((bfu(f0.z) + bfu(f1.z)) + (bfu(f2.z) + bfu(f3.z))) +
              ((bfu(f4.z) + bfu(f5.z)) + (bfu(f6.z) + bfu(f7.z)));
        h3 += ((bfu(f0.w) + bfu(f1.w)) + (bfu(f2.w) + bfu(f3.w))) +
              ((bfu(f4.w) + bfu(f5.w)) + (bfu(f6.w) + bfu(f7.w)));
        eacc += ((e0 + e1) + (e2 + e3)) + ((e4 + e5) + (e6 + e7));
    }
    if (p + 4 <= end) {
        int2 i0 = s_se[p + 0], i1 = s_se[p + 1], i2 = s_se[p + 2], i3 = s_se[p + 3];
        ushort4 f0 = *(const ushort4*)&featb[(size_t)i0.x * FIN + lane * 4];
        ushort4 f1 = *(const ushort4*)&featb[(size_t)i1.x * FIN + lane * 4];
        ushort4 f2 = *(const ushort4*)&featb[(size_t)i2.x * FIN + lane * 4];
        ushort4 f3 = *(const ushort4*)&featb[(size_t)i3.x * FIN + lane * 4];
        float e0 = __builtin_nontemporal_load(&edge_feat[(size_t)i0.y * FE + lane]);
        float e1 = __builtin_nontemporal_load(&edge_feat[(size_t)i1.y * FE + lane]);
        float e2 = __builtin_nontemporal_load(&edge_feat[(size_t)i2.y * FE + lane]);
        float e3 = __builtin_nontemporal_load(&edge_feat[(size_t)i3.y * FE + lane]);
        h0 += (bfu(f0.x) + bfu(f1.x)) + (bfu(f2.x) + bfu(f3.x));
        h1 += (bfu(f0.y) + bfu(f1.y)) + (bfu(f2.y) + bfu(f3.y));
        h2 += (bfu(f0.z) + bfu(f1.z)) + (bfu(f2.z) + bfu(f3.z));
        h3 += (bfu(f0.w) + bfu(f1.w)) + (bfu(f2.w) + bfu(f3.w));
        eacc += (e0 + e1) + (e2 + e3);
        p += 4;
    }
    for (; p < end; p++) {
        int2 a = s_se[p];
        ushort4 f0 = *(const ushort4*)&featb[(size_t)a.x * FIN + lane * 4];
        h0 += bfu(f0.x); h1 += bfu(f0.y); h2 += bfu(f0.z); h3 += bfu(f0.w);
        eacc += __builtin_nontemporal_load(&edge_feat[(size_t)a.y * FE + lane]);
    }

    ushort4 o;
    o.x = f2bf(h0); o.y = f2bf(h1); o.z = f2bf(h2); o.w = f2bf(h3);
    *(ushort4*)&aggb[(size_t)n * KTOT + lane * 4] = o;    // channels 0..255
    aggb[(size_t)n * KTOT + FIN + lane] = f2bf(eacc);     // channels 256..319
}

// ---------------- pass 5: MFMA GEMM K=320, fused epilogue relu(norm_in*X + bias) ----

#define GTM 128
#define GBK 64
#define ALD 72   // LDS row stride in bf16 (64+8 pad)

__global__ __launch_bounds__(256) void k_gemm_fused(const unsigned short* __restrict__ A,
                                                    int M,
                                                    const unsigned short* __restrict__ Wt,
                                                    const float* __restrict__ norm_in,
                                                    const float* __restrict__ bias,
                                                    float* __restrict__ out) {
    __shared__ unsigned short As[GTM * ALD];
    __shared__ unsigned short Bs[GTM * ALD];
    int m0 = blockIdx.y * GTM;
    int n0 = blockIdx.x * GTM;
    int t = threadIdx.x;
    int wave = t >> 6, lane = t & 63;
    int wy = wave >> 1, wx = wave & 1;
    int quad = lane >> 4, l16 = lane & 15;

    f32x4 acc[4][4];
#pragma unroll
    for (int i = 0; i < 4; i++)
#pragma unroll
        for (int j = 0; j < 4; j++) acc[i][j] = (f32x4){0.f, 0.f, 0.f, 0.f};

    for (int k0 = 0; k0 < KTOT; k0 += GBK) {
#pragma unroll
        for (int q = 0; q < 4; q++) {
            int idx = t + q * 256;
            int row = idx >> 3;
            int c16 = idx & 7;
            int gm = m0 + row;
            uint4 v = make_uint4(0, 0, 0, 0);
            if (gm < M) v = *(const uint4*)&A[(size_t)gm * KTOT + k0 + c16 * 8];
            *(uint4*)&As[row * ALD + c16 * 8] = v;
        }
#pragma unroll
        for (int q = 0; q < 4; q++) {
            int idx = t + q * 256;
            int row = idx >> 3;
            int c16 = idx & 7;
            uint4 v = *(const uint4*)&Wt[(size_t)(n0 + row) * KTOT + k0 + c16 * 8];
            *(uint4*)&Bs[row * ALD + c16 * 8] = v;
        }
        __syncthreads();
#pragma unroll
        for (int kk = 0; kk < GBK / 32; kk++) {
            short8 af[4], bf[4];
#pragma unroll
            for (int i = 0; i < 4; i++) {
                af[i] = *(const short8*)&As[(wy * 64 + i * 16 + l16) * ALD + kk * 32 + quad * 8];
                bf[i] = *(const short8*)&Bs[(wx * 64 + i * 16 + l16) * ALD + kk * 32 + quad * 8];
            }
#pragma unroll
            for (int i = 0; i < 4; i++)
#pragma unroll
                for (int j = 0; j < 4; j++)
                    acc[i][j] = __builtin_amdgcn_mfma_f32_16x16x32_bf16(af[i], bf[j], acc[i][j], 0, 0, 0);
        }
        __syncthreads();
    }

#pragma unroll
    for (int i = 0; i < 4; i++)
#pragma unroll
        for (int r = 0; r < 4; r++) {
            int gm = m0 + wy * 64 + i * 16 + quad * 4 + r;
            if (gm < M) {
                float ni = norm_in[gm];
#pragma unroll
                for (int j = 0; j < 4; j++) {
                    int gn = n0 + wx * 64 + j * 16 + l16;
                    float v = fmaxf(acc[i][j][r] * ni + bias[gn], 0.f);
                    out[(size_t)gm * FOUT + gn] = v;
                }
            }
        }
}

// ---------------- launch ----------------

extern "C" void kernel_launch(void* const* d_in, const int* in_sizes, int n_in,
                              void* d_out, int out_size, void* d_ws, size_t ws_size,
                              hipStream_t stream) {
    const float* feat      = (const float*)d_in[0];
    const float* edge_feat = (const float*)d_in[1];
    const float* weight    = (const float*)d_in[2];
    const float* bias      = (const float*)d_in[3];
    const int*   src       = (const int*)d_in[4];
    const int*   dst       = (const int*)d_in[5];
    int E = in_sizes[4];
    int N = in_sizes[0] / FIN;

    char* ws = (char*)d_ws;
    size_t off = 0;
    auto alloc = [&](size_t bytes) -> void* {
        void* p = ws + off;
        off += (bytes + 255) & ~(size_t)255;
        return p;
    };
    unsigned short* featb = (unsigned short*)alloc((size_t)N * FIN * 2);    // 25.6 MB
    unsigned short* aggb  = (unsigned short*)alloc((size_t)N * KTOT * 2);   // 32 MB
    unsigned short* wtt   = (unsigned short*)alloc((size_t)256 * KTOT * 2);
    // degree arrays: ONE allocation of 2N ints so in_deg = out_deg + N exactly,
    // and a single memset covers both (round-7 crash: allocator 256B-rounding
    // broke the adjacency assumption).
    int*   out_deg  = (int*)alloc((size_t)2 * N * 4);
    int*   in_deg   = out_deg + N;
    int*   row_ptr  = (int*)alloc((size_t)(N + 1) * 4);
    int*   cursor   = (int*)alloc((size_t)N * 4);
    float* norm_out = (float*)alloc((size_t)N * 4);
    float* norm_in  = (float*)alloc((size_t)N * 4);
    int2*  s_se     = (int2*)alloc((size_t)E * 8);
    (void)ws_size;

    int bE = (E + 255) / 256;
    int nchunk = (N + 1023) >> 10;

    hipMemsetAsync(out_deg, 0, (size_t)2 * N * 4, stream);

    k_deg_prepw<<<bE, 256, 0, stream>>>(src, dst, out_deg, in_deg, weight, wtt, E);
    k_scan<<<nchunk, 1024, 0, stream>>>(in_deg, out_deg, row_ptr, cursor,
                                        norm_out, norm_in, N);
    k_scatter_prepf<<<(N * 64 + 255) / 256, 256, 0, stream>>>(src, dst, cursor, s_se, E,
                                                              feat, norm_out, featb, N);

    // fused aggregation: aggb[n] = [sum featb[src], sum edge_feat[eid]] (bf16), 1 wave/node
    k_agg<<<(N + 3) / 4, 256, 0, stream>>>(featb, edge_feat, row_ptr, s_se, aggb, N);

    // fused GEMM + epilogue: out = relu(norm_in * (aggb @ Wt) + bias)
    dim3 gg(FOUT / GTM, (N + GTM - 1) / GTM);
    k_gemm_fused<<<gg, 256, 0, stream>>>(aggb, N, wtt, norm_in, bias, (float*)d_out);
}